// Round 4
// baseline (1880.887 us; speedup 1.0000x reference)
//
#include <hip/hip_runtime.h>
#include <hip/hip_fp16.h>

// GNN: fc1 -> GCNConv x2 -> mean-pool -> L2norm -> fc2
// N=100000, E=1.6M, F=H=128, O=64, G=1024.
// R3: panel-blocked aggregation with (a) XCD-pinned panels (panel = bid&7,
// round-robin block->XCD => each XCD's L2 holds ONE 3.2MB panel table ->
// gathers are L2 hits) and (b) broadcast CSR loads (8 lanes/group read the
// same 4B address) instead of shfl -> ~4x less VALU than R2.

#define CHK 1024  // scan chunk size
typedef unsigned int u32;

__global__ __launch_bounds__(256) void k_transpose128(const float* __restrict__ W,
                                                      float* __restrict__ WT) {
  int t = blockIdx.x * 256 + threadIdx.x;  // 0..16383
  int o = t >> 7, k = t & 127;
  WT[k * 128 + o] = W[t];
}

__global__ __launch_bounds__(256) void k_hist(const int* __restrict__ dst,
                                              const float* __restrict__ w,
                                              int* __restrict__ cnt,
                                              float* __restrict__ degf, int E) {
  int e = blockIdx.x * 256 + threadIdx.x;
  if (e < E) {
    int d = dst[e];
    atomicAdd(&cnt[d], 1);
    atomicAdd(&degf[d], w[e]);
  }
}

__global__ __launch_bounds__(256) void k_dis(const float* __restrict__ degf,
                                             float* __restrict__ dis,
                                             float* __restrict__ inv, int N) {
  int n = blockIdx.x * 256 + threadIdx.x;
  if (n < N) {
    float deg = degf[n] + 1.0f;  // self-loop weight 1
    dis[n] = rsqrtf(deg);
    inv[n] = 1.0f / deg;
  }
}

__global__ __launch_bounds__(256) void k_scan_reduce(const int* __restrict__ cnt,
                                                     int* __restrict__ chunkSum, int N) {
  __shared__ int sd[256];
  int b = blockIdx.x, t = threadIdx.x;
  int base = b * CHK + t * 4;
  int s = 0;
#pragma unroll
  for (int i = 0; i < 4; i++)
    if (base + i < N) s += cnt[base + i];
  sd[t] = s;
  __syncthreads();
  for (int off = 128; off; off >>= 1) {
    if (t < off) sd[t] += sd[t + off];
    __syncthreads();
  }
  if (t == 0) chunkSum[b] = sd[0];
}

__global__ void k_scan_chunks(const int* __restrict__ chunkSum,
                              int* __restrict__ chunkOff, int NC) {
  if (threadIdx.x == 0 && blockIdx.x == 0) {
    int s = 0;
    for (int i = 0; i < NC; i++) {
      chunkOff[i] = s;
      s += chunkSum[i];
    }
  }
}

__global__ __launch_bounds__(256) void k_scan_final(const int* __restrict__ cnt,
                                                    const int* __restrict__ chunkOff,
                                                    int* __restrict__ rowptr,
                                                    int* __restrict__ cursor, int N, int E) {
  __shared__ int sd[256];
  int b = blockIdx.x, t = threadIdx.x;
  int base = b * CHK + t * 4;
  int v[4], loc[4];
#pragma unroll
  for (int i = 0; i < 4; i++) v[i] = (base + i < N) ? cnt[base + i] : 0;
  loc[0] = 0;
  loc[1] = v[0];
  loc[2] = v[0] + v[1];
  loc[3] = v[0] + v[1] + v[2];
  int tot = loc[3] + v[3];
  sd[t] = tot;
  __syncthreads();
  for (int off = 1; off < 256; off <<= 1) {
    int xv = (t >= off) ? sd[t - off] : 0;
    __syncthreads();
    sd[t] += xv;
    __syncthreads();
  }
  int tbase = (t ? sd[t - 1] : 0) + chunkOff[b];
#pragma unroll
  for (int i = 0; i < 4; i++) {
    if (base + i < N) {
      int r = tbase + loc[i];
      rowptr[base + i] = r;
      cursor[base + i] = r;
    }
  }
  if (b == 0 && t == 0) rowptr[N] = E;
}

__global__ __launch_bounds__(256) void k_scatter(const int* __restrict__ src,
                                                 const int* __restrict__ dst,
                                                 const float* __restrict__ w,
                                                 const float* __restrict__ dis,
                                                 int* __restrict__ cursor,
                                                 int* __restrict__ csr_src,
                                                 float* __restrict__ csr_c, int E) {
  int e = blockIdx.x * 256 + threadIdx.x;
  if (e < E) {
    int s = src[e], d = dst[e];
    float c = w[e] * dis[s] * dis[d];
    int p = atomicAdd(&cursor[d], 1);
    csr_src[p] = s;
    csr_c[p] = c;
  }
}

// C[n][o] = sum_k A[n][k] * W[o][k]; optional bias+PReLU.
// HALF_OUT: write fp16 PANEL-MAJOR: Ch[((panel*N + n)*8 + half2_idx)],
// panel = feat>>4 (8 panels x 16 feats).
template <bool HALF_OUT>
__global__ __launch_bounds__(256) void k_gemm128(const float* __restrict__ A,
                                                 const float* __restrict__ WT,
                                                 float* __restrict__ C,
                                                 __half2* __restrict__ Ch,
                                                 const float* __restrict__ bias,
                                                 const float* __restrict__ slope,
                                                 int N) {
  __shared__ float xs[32 * 128];
  int t = threadIdx.x;
  size_t base = (size_t)blockIdx.x * 32;
  {
    const float4* s4 = (const float4*)(A + base * 128);
    float4* d4 = (float4*)xs;
#pragma unroll
    for (int i = 0; i < 4; i++) d4[t + 256 * i] = s4[t + 256 * i];
  }
  __syncthreads();
  int cg = (t & 31) * 4;   // col base (0..124)
  int ng = (t >> 5) * 4;   // node base within tile (0..28)
  float acc[4][4];
#pragma unroll
  for (int u = 0; u < 4; u++)
#pragma unroll
    for (int c = 0; c < 4; c++) acc[u][c] = 0.f;

#pragma unroll 2
  for (int k0 = 0; k0 < 128; k0 += 4) {
    float4 xq[4];
#pragma unroll
    for (int u = 0; u < 4; u++) xq[u] = *(const float4*)&xs[(ng + u) * 128 + k0];
#pragma unroll
    for (int j = 0; j < 4; j++) {
      float4 wt = *(const float4*)&WT[(k0 + j) * 128 + cg];
#pragma unroll
      for (int u = 0; u < 4; u++) {
        float xv = ((const float*)&xq[u])[j];
        acc[u][0] += xv * wt.x;
        acc[u][1] += xv * wt.y;
        acc[u][2] += xv * wt.z;
        acc[u][3] += xv * wt.w;
      }
    }
  }
  float a = slope ? *slope : 1.0f;
#pragma unroll
  for (int u = 0; u < 4; u++) {
    size_t n = base + ng + u;
    float4 o;
    o.x = acc[u][0]; o.y = acc[u][1]; o.z = acc[u][2]; o.w = acc[u][3];
    if (bias) {
      o.x += bias[cg]; o.y += bias[cg + 1]; o.z += bias[cg + 2]; o.w += bias[cg + 3];
    }
    if (slope) {
      o.x = o.x >= 0.f ? o.x : a * o.x;
      o.y = o.y >= 0.f ? o.y : a * o.y;
      o.z = o.z >= 0.f ? o.z : a * o.z;
      o.w = o.w >= 0.f ? o.w : a * o.w;
    }
    if (HALF_OUT) {
      __half2 h0 = __float22half2_rn(make_float2(o.x, o.y));
      __half2 h1 = __float22half2_rn(make_float2(o.z, o.w));
      int pp = cg >> 4;          // panel
      int f = cg & 15;           // feat within panel (0,4,8,12)
      size_t hidx = ((size_t)pp * N + n) * 8 + (f >> 1);
      uint2 pk;
      pk.x = *(u32*)&h0;
      pk.y = *(u32*)&h1;
      *(uint2*)&Ch[hidx] = pk;   // hidx even -> 8B aligned
    } else {
      *(float4*)&C[n * 128 + cg] = o;
    }
  }
}

// XCD-pinned panel-blocked pull aggregation.
// panel = blockIdx.x & 7  (round-robin block->XCD => XCD i works panel i only;
// panel table = 3.2MB -> L2-resident gathers).
// Wave per (node,panel): lanes split g=l>>3 (edge slot), sub=l&7 (half2 in
// 32B panel row). CSR read via group-broadcast loads (no shfl).
template <bool POOL>
__global__ __launch_bounds__(256) void k_agg_p(const __half2* __restrict__ hWp,
                                               const int* __restrict__ rowptr,
                                               const int* __restrict__ csr_src,
                                               const float* __restrict__ csr_c,
                                               const float* __restrict__ inv,
                                               const float* __restrict__ bias,
                                               const float* __restrict__ slope,
                                               const int* __restrict__ batch,
                                               float* __restrict__ out,
                                               float* __restrict__ cntg, int N) {
  int panel = blockIdx.x & 7;
  int node = (blockIdx.x >> 3) * 4 + (threadIdx.x >> 6);
  if (node >= N) return;
  int l = threadIdx.x & 63;
  int g = l >> 3, sub = l & 7;
  const __half2* tab = hWp + (size_t)panel * N * 8;
  int r0 = rowptr[node], r1 = rowptr[node + 1];
  int r1m1 = r1 - 1;
  float2 acc = make_float2(0.f, 0.f);
  for (int base = r0; base < r1; base += 16) {
#pragma unroll
    for (int u = 0; u < 2; u++) {
      int idx = base + u * 8 + g;
      bool valid = idx < r1;
      int ic = valid ? idx : r1m1;          // clamp; loop ran => r1m1 >= r0 >= 0
      int s = csr_src[ic];                  // 8 lanes/group same addr: broadcast
      float c = valid ? csr_c[ic] : 0.f;
      float2 f = __half22float2(tab[(size_t)s * 8 + sub]);
      acc.x += f.x * c;
      acc.y += f.y * c;
    }
  }
  // reduce over the 8 edge-slot groups
#pragma unroll
  for (int off = 8; off < 64; off <<= 1) {
    acc.x += __shfl_xor(acc.x, off);
    acc.y += __shfl_xor(acc.y, off);
  }
  if (l < 8) {  // g==0, sub = l
    float2 own = __half22float2(tab[(size_t)node * 8 + sub]);
    float iv = inv[node];
    acc.x += own.x * iv;
    acc.y += own.y * iv;
    float a = *slope;
    float2 b = *(const float2*)&bias[panel * 16 + sub * 2];
    acc.x += b.x;
    acc.y += b.y;
    acc.x = acc.x >= 0.f ? acc.x : a * acc.x;
    acc.y = acc.y >= 0.f ? acc.y : a * acc.y;
    if (POOL) {
      int gb = batch[node];
      atomicAdd(&out[(size_t)gb * 128 + panel * 16 + sub * 2], acc.x);
      atomicAdd(&out[(size_t)gb * 128 + panel * 16 + sub * 2 + 1], acc.y);
      if (panel == 0 && sub == 0) atomicAdd(&cntg[gb], 1.0f);
    } else {
      *(float2*)&out[(size_t)node * 128 + panel * 16 + sub * 2] = acc;
    }
  }
}

// Per-graph: mean, L2-normalize, out = hg @ fc2_w.T + fc2_b.  1 wave/graph.
__global__ __launch_bounds__(64) void k_final(const float* __restrict__ pool,
                                              const float* __restrict__ cntg,
                                              const float* __restrict__ fc2w,
                                              const float* __restrict__ fc2b,
                                              float* __restrict__ out) {
  __shared__ float hg[128];
  int g = blockIdx.x, l = threadIdx.x;
  float cnt = cntg[g];
  float ic = 1.0f / fmaxf(cnt, 1.0f);
  float2 v = *(const float2*)&pool[(size_t)g * 128 + l * 2];
  v.x *= ic;
  v.y *= ic;
  float ss = v.x * v.x + v.y * v.y;
#pragma unroll
  for (int off = 1; off < 64; off <<= 1) ss += __shfl_xor(ss, off);
  float nrm = sqrtf(ss);
  float sc = 1.0f / fmaxf(nrm, 1e-12f);
  hg[l * 2] = v.x * sc;
  hg[l * 2 + 1] = v.y * sc;
  __syncthreads();
  float acc = fc2b[l];
#pragma unroll 4
  for (int k = 0; k < 128; k++) acc += hg[k] * fc2w[l * 128 + k];
  out[(size_t)g * 64 + l] = acc;
}

extern "C" void kernel_launch(void* const* d_in, const int* in_sizes, int n_in,
                              void* d_out, int out_size, void* d_ws, size_t ws_size,
                              hipStream_t stream) {
  const float* x = (const float*)d_in[0];
  const int* ei = (const int*)d_in[1];
  const float* ew = (const float*)d_in[2];
  const int* batch = (const int*)d_in[3];
  const float* fc1_w = (const float*)d_in[4];
  const float* fc1_b = (const float*)d_in[5];
  const float* gc1_w = (const float*)d_in[6];
  const float* gc1_b = (const float*)d_in[7];
  const float* gc2_w = (const float*)d_in[8];
  const float* gc2_b = (const float*)d_in[9];
  const float* fc2_w = (const float*)d_in[10];
  const float* fc2_b = (const float*)d_in[11];
  const float* a_fc1 = (const float*)d_in[12];
  const float* a_gc1 = (const float*)d_in[13];
  const float* a_gc2 = (const float*)d_in[14];

  int N = in_sizes[0] / 128;
  int E = in_sizes[2];
  int G = out_size / 64;
  const int* src = ei;
  const int* dst = ei + E;

  char* p = (char*)d_ws;
  auto carve = [&](size_t bytes) -> char* {
    char* r = p;
    p += (bytes + 255) & ~(size_t)255;
    return r;
  };
  float* bufA = (float*)carve((size_t)N * 128 * 4);
  __half2* bufH = (__half2*)carve((size_t)N * 64 * 4);  // fp16 hW, panel-major
  int* csr_src = (int*)carve((size_t)E * 4);
  float* csr_c = (float*)carve((size_t)E * 4);
  int* cnt = (int*)carve((size_t)N * 4);
  int* rowptr = (int*)carve((size_t)(N + 1) * 4);
  int* cursor = (int*)carve((size_t)N * 4);
  float* degf = (float*)carve((size_t)N * 4);
  float* dis = (float*)carve((size_t)N * 4);
  float* inv = (float*)carve((size_t)N * 4);
  float* WT1 = (float*)carve(16384 * 4);
  float* WT2 = (float*)carve(16384 * 4);
  float* WT3 = (float*)carve(16384 * 4);
  int NC = (N + CHK - 1) / CHK;
  int* chunkSum = (int*)carve((size_t)NC * 4);
  int* chunkOff = (int*)carve((size_t)NC * 4);
  float* pool = (float*)carve((size_t)G * 128 * 4);
  float* cntg = (float*)carve((size_t)G * 4);

  hipMemsetAsync(cnt, 0, (size_t)N * 4, stream);
  hipMemsetAsync(degf, 0, (size_t)N * 4, stream);
  hipMemsetAsync(pool, 0, (size_t)G * 128 * 4, stream);
  hipMemsetAsync(cntg, 0, (size_t)G * 4, stream);

  k_transpose128<<<64, 256, 0, stream>>>(fc1_w, WT1);
  k_transpose128<<<64, 256, 0, stream>>>(gc1_w, WT2);
  k_transpose128<<<64, 256, 0, stream>>>(gc2_w, WT3);

  int gE = (E + 255) / 256;
  int gN = (N + 255) / 256;
  k_hist<<<gE, 256, 0, stream>>>(dst, ew, cnt, degf, E);
  k_dis<<<gN, 256, 0, stream>>>(degf, dis, inv, N);
  k_scan_reduce<<<NC, 256, 0, stream>>>(cnt, chunkSum, N);
  k_scan_chunks<<<1, 64, 0, stream>>>(chunkSum, chunkOff, NC);
  k_scan_final<<<NC, 256, 0, stream>>>(cnt, chunkOff, rowptr, cursor, N, E);
  k_scatter<<<gE, 256, 0, stream>>>(src, dst, ew, dis, cursor, csr_src, csr_c, E);

  // h = prelu(x @ fc1_w.T + fc1_b)  -> bufA (fp32)
  k_gemm128<false><<<N / 32, 256, 0, stream>>>(x, WT1, bufA, nullptr, fc1_b, a_fc1, N);

  int gAgg = 8 * ((N + 3) / 4);  // panel = bid&7 (XCD pin), 4 nodes/block
  // conv1: hW = h @ gc1_w.T (fp16 panel-major) ; aggregate -> bufA
  k_gemm128<true><<<N / 32, 256, 0, stream>>>(bufA, WT2, nullptr, bufH, nullptr, nullptr, N);
  k_agg_p<false><<<gAgg, 256, 0, stream>>>(bufH, rowptr, csr_src, csr_c, inv, gc1_b, a_gc1,
                                           batch, bufA, cntg, N);
  // conv2: hW = h @ gc2_w.T ; aggregate + pool (fused)
  k_gemm128<true><<<N / 32, 256, 0, stream>>>(bufA, WT3, nullptr, bufH, nullptr, nullptr, N);
  k_agg_p<true><<<gAgg, 256, 0, stream>>>(bufH, rowptr, csr_src, csr_c, inv, gc2_b, a_gc2,
                                          batch, pool, cntg, N);
  k_final<<<G, 64, 0, stream>>>(pool, cntg, fc2_w, fc2_b, (float*)d_out);
}

// Round 5
// 567.422 us; speedup vs baseline: 3.3148x; 3.3148x over previous
//
#include <hip/hip_runtime.h>
#include <hip/hip_fp16.h>

// GNN: fc1 -> GCNConv x2 -> mean-pool -> L2norm -> fc2
// N=100000, E=1.6M, F=H=128, O=64, G=1024.
// R4: aggregation reverted to R2 structure (wave/node, reg-held CSR + shfl
// broadcast, 8 gathers in flight, fp16 rows) with int2-packed CSR.
// GEMMs switched to MFMA 16x16x32_f16: B pre-packed to fragment layout,
// A-fragments loaded straight from global, fp32 accum, LDS-transpose store.

#define CHK 1024  // scan chunk size
typedef unsigned int u32;
using f16 = _Float16;
using f16x8 = __attribute__((ext_vector_type(8))) _Float16;
using f32x4 = __attribute__((ext_vector_type(4))) float;

__global__ __launch_bounds__(256) void k_hist(const int* __restrict__ dst,
                                              const float* __restrict__ w,
                                              int* __restrict__ cnt,
                                              float* __restrict__ degf, int E) {
  int e = blockIdx.x * 256 + threadIdx.x;
  if (e < E) {
    int d = dst[e];
    atomicAdd(&cnt[d], 1);
    atomicAdd(&degf[d], w[e]);
  }
}

__global__ __launch_bounds__(256) void k_dis(const float* __restrict__ degf,
                                             float* __restrict__ dis,
                                             float* __restrict__ inv, int N) {
  int n = blockIdx.x * 256 + threadIdx.x;
  if (n < N) {
    float deg = degf[n] + 1.0f;  // self-loop weight 1
    dis[n] = rsqrtf(deg);
    inv[n] = 1.0f / deg;
  }
}

__global__ __launch_bounds__(256) void k_scan_reduce(const int* __restrict__ cnt,
                                                     int* __restrict__ chunkSum, int N) {
  __shared__ int sd[256];
  int b = blockIdx.x, t = threadIdx.x;
  int base = b * CHK + t * 4;
  int s = 0;
#pragma unroll
  for (int i = 0; i < 4; i++)
    if (base + i < N) s += cnt[base + i];
  sd[t] = s;
  __syncthreads();
  for (int off = 128; off; off >>= 1) {
    if (t < off) sd[t] += sd[t + off];
    __syncthreads();
  }
  if (t == 0) chunkSum[b] = sd[0];
}

__global__ void k_scan_chunks(const int* __restrict__ chunkSum,
                              int* __restrict__ chunkOff, int NC) {
  if (threadIdx.x == 0 && blockIdx.x == 0) {
    int s = 0;
    for (int i = 0; i < NC; i++) {
      chunkOff[i] = s;
      s += chunkSum[i];
    }
  }
}

__global__ __launch_bounds__(256) void k_scan_final(const int* __restrict__ cnt,
                                                    const int* __restrict__ chunkOff,
                                                    int* __restrict__ rowptr,
                                                    int* __restrict__ cursor, int N, int E) {
  __shared__ int sd[256];
  int b = blockIdx.x, t = threadIdx.x;
  int base = b * CHK + t * 4;
  int v[4], loc[4];
#pragma unroll
  for (int i = 0; i < 4; i++) v[i] = (base + i < N) ? cnt[base + i] : 0;
  loc[0] = 0;
  loc[1] = v[0];
  loc[2] = v[0] + v[1];
  loc[3] = v[0] + v[1] + v[2];
  int tot = loc[3] + v[3];
  sd[t] = tot;
  __syncthreads();
  for (int off = 1; off < 256; off <<= 1) {
    int xv = (t >= off) ? sd[t - off] : 0;
    __syncthreads();
    sd[t] += xv;
    __syncthreads();
  }
  int tbase = (t ? sd[t - 1] : 0) + chunkOff[b];
#pragma unroll
  for (int i = 0; i < 4; i++) {
    if (base + i < N) {
      int r = tbase + loc[i];
      rowptr[base + i] = r;
      cursor[base + i] = r;
    }
  }
  if (b == 0 && t == 0) rowptr[N] = E;
}

__global__ __launch_bounds__(256) void k_scatter(const int* __restrict__ src,
                                                 const int* __restrict__ dst,
                                                 const float* __restrict__ w,
                                                 const float* __restrict__ dis,
                                                 int* __restrict__ cursor,
                                                 int2* __restrict__ csr, int E) {
  int e = blockIdx.x * 256 + threadIdx.x;
  if (e < E) {
    int s = src[e], d = dst[e];
    float c = w[e] * dis[s] * dis[d];
    int p = atomicAdd(&cursor[d], 1);
    int2 v;
    v.x = s;
    v.y = __float_as_int(c);
    csr[p] = v;
  }
}

// Pack W [128][128] row-major (W[o][k], fp32) into MFMA B-fragment order:
// Bf[(kc*8+ct)*64 + lane][i] = f16(W[ct*16 + (lane&15)][kc*32 + (lane>>4)*8 + i])
__global__ __launch_bounds__(256) void k_prep_bfrag(const float* __restrict__ W,
                                                    f16x8* __restrict__ Bf) {
  int t = blockIdx.x * 256 + threadIdx.x;  // 0..2047
  int combo = t >> 6;                      // kc*8+ct
  int l = t & 63;
  int o = (combo & 7) * 16 + (l & 15);
  int k0 = (combo >> 3) * 32 + (l >> 4) * 8;
  f16x8 b;
#pragma unroll
  for (int i = 0; i < 8; i++) b[i] = (f16)W[o * 128 + k0 + i];
  Bf[combo * 64 + l] = b;
}

// MFMA GEMM: out[n][o] = act( sum_k A[n][k]*W[o][k] (+bias) ).
// 4 waves/block, 16 nodes/wave, full 128 out cols, fp32 accum, fp16 out.
// FP32_IN: A is fp32 (fc1 path, converts in-register). BIAS: bias+PReLU.
template <bool FP32_IN, bool BIAS>
__global__ __launch_bounds__(256) void k_gemm_mfma(const f16* __restrict__ Ah,
                                                   const float* __restrict__ Af,
                                                   const f16x8* __restrict__ Bf,
                                                   f16* __restrict__ out,
                                                   const float* __restrict__ bias,
                                                   const float* __restrict__ slope,
                                                   int N) {
  __shared__ f16 ls[64 * 128];
  int t = threadIdx.x;
  int w = t >> 6, l = t & 63;
  int l15 = l & 15, kgrp = l >> 4;
  int nodeBase = blockIdx.x * 64 + w * 16;
  f32x4 acc[8];
#pragma unroll
  for (int ct = 0; ct < 8; ct++)
#pragma unroll
    for (int j = 0; j < 4; j++) acc[ct][j] = 0.f;

  int arow = nodeBase + l15;
  if (arow >= N) arow = N - 1;  // clamp: duplicate read, store is guarded
#pragma unroll
  for (int kc = 0; kc < 4; kc++) {
    f16x8 a;
    if (FP32_IN) {
      const float4* p0 = (const float4*)(Af + (size_t)arow * 128 + kc * 32 + kgrp * 8);
      float4 x0 = p0[0], x1 = p0[1];
      a[0] = (f16)x0.x; a[1] = (f16)x0.y; a[2] = (f16)x0.z; a[3] = (f16)x0.w;
      a[4] = (f16)x1.x; a[5] = (f16)x1.y; a[6] = (f16)x1.z; a[7] = (f16)x1.w;
    } else {
      a = *(const f16x8*)(Ah + (size_t)arow * 128 + kc * 32 + kgrp * 8);
    }
#pragma unroll
    for (int ct = 0; ct < 8; ct++) {
      f16x8 b = Bf[(kc * 8 + ct) * 64 + l];
      acc[ct] = __builtin_amdgcn_mfma_f32_16x16x32_f16(a, b, acc[ct], 0, 0, 0);
    }
  }
  // Epilogue: C/D layout col=l&15, row=(l>>4)*4+j  [HW-verified m89].
  float sl = BIAS ? *slope : 0.f;
  f16* slab = ls + w * 16 * 128;
#pragma unroll
  for (int ct = 0; ct < 8; ct++) {
    float bv = BIAS ? bias[ct * 16 + l15] : 0.f;
#pragma unroll
    for (int j = 0; j < 4; j++) {
      float v = acc[ct][j];
      if (BIAS) {
        v += bv;
        v = v >= 0.f ? v : sl * v;
      }
      slab[(kgrp * 4 + j) * 128 + ct * 16 + l15] = (f16)v;
    }
  }
  __syncthreads();
  // Coalesced store: lane l -> row l>>2, chunks (l&3)+4i (16B each).
  {
    int r = l >> 2;
    int gnode = nodeBase + r;
    if (gnode < N) {
      const uint4* srcp = (const uint4*)(slab + r * 128);
      uint4* dstp = (uint4*)(out + (size_t)gnode * 128);
#pragma unroll
      for (int i = 0; i < 4; i++) {
        int chunk = (l & 3) + i * 4;
        dstp[chunk] = srcp[chunk];
      }
    }
  }
}

// Pull aggregation (R2 structure): wave per dst node; hW fp16 rows (64 half2);
// reg-held CSR (int2) + shfl broadcast; 8 gathers in flight; fp32 accum.
// !POOL: write fp16 row (next GEMM input). POOL: atomic fp32 pool accumulate.
template <bool POOL>
__global__ __launch_bounds__(256) void k_agg_h(const __half2* __restrict__ hW,
                                               const int* __restrict__ rowptr,
                                               const int2* __restrict__ csr,
                                               const float* __restrict__ inv,
                                               const float* __restrict__ bias,
                                               const float* __restrict__ slope,
                                               const int* __restrict__ batch,
                                               __half2* __restrict__ outh,
                                               float* __restrict__ pool,
                                               float* __restrict__ cntg, int N) {
  int wid = (blockIdx.x * 256 + threadIdx.x) >> 6;
  if (wid >= N) return;
  int l = threadIdx.x & 63;
  int r0 = rowptr[wid], r1 = rowptr[wid + 1];
  float2 acc;
  {
    float2 f = __half22float2(hW[(size_t)wid * 64 + l]);
    float iv = inv[wid];
    acc.x = f.x * iv;
    acc.y = f.y * iv;
  }
  for (int base = r0; base < r1; base += 64) {
    int idx = base + l;
    int sl = 0;
    float cl = 0.f;
    if (idx < r1) {
      int2 e = csr[idx];
      sl = e.x;
      cl = __int_as_float(e.y);
    }
    int m = min(64, r1 - base);
    for (int k = 0; k < m; k += 8) {
      __half2 v[8];
      float c[8];
#pragma unroll
      for (int i = 0; i < 8; i++) {
        int s = __shfl(sl, k + i);
        c[i] = __shfl(cl, k + i);
        v[i] = hW[(size_t)s * 64 + l];  // OOB edges: s=0,c=0 -> harmless hot line
      }
#pragma unroll
      for (int i = 0; i < 8; i++) {
        float2 f = __half22float2(v[i]);
        acc.x += f.x * c[i];
        acc.y += f.y * c[i];
      }
    }
  }
  float a = *slope;
  float2 b = *(const float2*)&bias[l * 2];
  acc.x += b.x;
  acc.y += b.y;
  acc.x = acc.x >= 0.f ? acc.x : a * acc.x;
  acc.y = acc.y >= 0.f ? acc.y : a * acc.y;
  if (POOL) {
    int g = batch[wid];
    atomicAdd(&pool[(size_t)g * 128 + l * 2], acc.x);
    atomicAdd(&pool[(size_t)g * 128 + l * 2 + 1], acc.y);
    if (l == 0) atomicAdd(&cntg[g], 1.0f);
  } else {
    outh[(size_t)wid * 64 + l] = __float22half2_rn(acc);
  }
}

// Per-graph: mean, L2-normalize, out = hg @ fc2_w.T + fc2_b.  1 wave/graph.
__global__ __launch_bounds__(64) void k_final(const float* __restrict__ pool,
                                              const float* __restrict__ cntg,
                                              const float* __restrict__ fc2w,
                                              const float* __restrict__ fc2b,
                                              float* __restrict__ out) {
  __shared__ float hg[128];
  int g = blockIdx.x, l = threadIdx.x;
  float cnt = cntg[g];
  float ic = 1.0f / fmaxf(cnt, 1.0f);
  float2 v = *(const float2*)&pool[(size_t)g * 128 + l * 2];
  v.x *= ic;
  v.y *= ic;
  float ss = v.x * v.x + v.y * v.y;
#pragma unroll
  for (int off = 1; off < 64; off <<= 1) ss += __shfl_xor(ss, off);
  float nrm = sqrtf(ss);
  float sc = 1.0f / fmaxf(nrm, 1e-12f);
  hg[l * 2] = v.x * sc;
  hg[l * 2 + 1] = v.y * sc;
  __syncthreads();
  float acc = fc2b[l];
#pragma unroll 4
  for (int k = 0; k < 128; k++) acc += hg[k] * fc2w[l * 128 + k];
  out[(size_t)g * 64 + l] = acc;
}

extern "C" void kernel_launch(void* const* d_in, const int* in_sizes, int n_in,
                              void* d_out, int out_size, void* d_ws, size_t ws_size,
                              hipStream_t stream) {
  const float* x = (const float*)d_in[0];
  const int* ei = (const int*)d_in[1];
  const float* ew = (const float*)d_in[2];
  const int* batch = (const int*)d_in[3];
  const float* fc1_w = (const float*)d_in[4];
  const float* fc1_b = (const float*)d_in[5];
  const float* gc1_w = (const float*)d_in[6];
  const float* gc1_b = (const float*)d_in[7];
  const float* gc2_w = (const float*)d_in[8];
  const float* gc2_b = (const float*)d_in[9];
  const float* fc2_w = (const float*)d_in[10];
  const float* fc2_b = (const float*)d_in[11];
  const float* a_fc1 = (const float*)d_in[12];
  const float* a_gc1 = (const float*)d_in[13];
  const float* a_gc2 = (const float*)d_in[14];

  int N = in_sizes[0] / 128;
  int E = in_sizes[2];
  int G = out_size / 64;
  const int* src = ei;
  const int* dst = ei + E;

  char* p = (char*)d_ws;
  auto carve = [&](size_t bytes) -> char* {
    char* r = p;
    p += (bytes + 255) & ~(size_t)255;
    return r;
  };
  f16* bufA = (f16*)carve((size_t)N * 128 * 2);       // h (fp16 rows)
  f16* bufH = (f16*)carve((size_t)N * 128 * 2);       // hW (fp16 rows)
  int2* csr = (int2*)carve((size_t)E * 8);            // (src, coef-bits)
  int* cnt = (int*)carve((size_t)N * 4);
  int* rowptr = (int*)carve((size_t)(N + 1) * 4);
  int* cursor = (int*)carve((size_t)N * 4);
  float* degf = (float*)carve((size_t)N * 4);
  float* dis = (float*)carve((size_t)N * 4);
  float* inv = (float*)carve((size_t)N * 4);
  f16x8* Bf1 = (f16x8*)carve(2048 * 16);
  f16x8* Bf2 = (f16x8*)carve(2048 * 16);
  f16x8* Bf3 = (f16x8*)carve(2048 * 16);
  int NC = (N + CHK - 1) / CHK;
  int* chunkSum = (int*)carve((size_t)NC * 4);
  int* chunkOff = (int*)carve((size_t)NC * 4);
  float* pool = (float*)carve((size_t)G * 128 * 4);
  float* cntg = (float*)carve((size_t)G * 4);

  hipMemsetAsync(cnt, 0, (size_t)N * 4, stream);
  hipMemsetAsync(degf, 0, (size_t)N * 4, stream);
  hipMemsetAsync(pool, 0, (size_t)G * 128 * 4, stream);
  hipMemsetAsync(cntg, 0, (size_t)G * 4, stream);

  k_prep_bfrag<<<8, 256, 0, stream>>>(fc1_w, Bf1);
  k_prep_bfrag<<<8, 256, 0, stream>>>(gc1_w, Bf2);
  k_prep_bfrag<<<8, 256, 0, stream>>>(gc2_w, Bf3);

  int gE = (E + 255) / 256;
  int gN = (N + 255) / 256;
  k_hist<<<gE, 256, 0, stream>>>(dst, ew, cnt, degf, E);
  k_dis<<<gN, 256, 0, stream>>>(degf, dis, inv, N);
  k_scan_reduce<<<NC, 256, 0, stream>>>(cnt, chunkSum, N);
  k_scan_chunks<<<1, 64, 0, stream>>>(chunkSum, chunkOff, NC);
  k_scan_final<<<NC, 256, 0, stream>>>(cnt, chunkOff, rowptr, cursor, N, E);
  k_scatter<<<gE, 256, 0, stream>>>(src, dst, ew, dis, cursor, csr, E);

  int gGemm = (N + 63) / 64;
  // h = prelu(x @ fc1_w.T + fc1_b) -> bufA (fp16)
  k_gemm_mfma<true, true><<<gGemm, 256, 0, stream>>>(nullptr, x, Bf1, bufA, fc1_b, a_fc1, N);
  // conv1: hW = h @ gc1_w.T -> bufH ; aggregate -> bufA
  k_gemm_mfma<false, false><<<gGemm, 256, 0, stream>>>(bufA, nullptr, Bf2, bufH, nullptr, nullptr, N);
  int gAgg = (int)(((size_t)N * 64 + 255) / 256);
  k_agg_h<false><<<gAgg, 256, 0, stream>>>((const __half2*)bufH, rowptr, csr, inv, gc1_b,
                                           a_gc1, batch, (__half2*)bufA, nullptr, cntg, N);
  // conv2: hW = h @ gc2_w.T -> bufH ; aggregate + pool (fused)
  k_gemm_mfma<false, false><<<gGemm, 256, 0, stream>>>(bufA, nullptr, Bf3, bufH, nullptr, nullptr, N);
  k_agg_h<true><<<gAgg, 256, 0, stream>>>((const __half2*)bufH, rowptr, csr, inv, gc2_b,
                                          a_gc2, batch, nullptr, pool, cntg, N);
  k_final<<<G, 64, 0, stream>>>(pool, cntg, fc2_w, fc2_b, (float*)d_out);
}